// Round 1
// baseline (711.928 us; speedup 1.0000x reference)
//
#include <hip/hip_runtime.h>
#include <math.h>

#define N_NODES 10000
#define IN_FEAT 512
#define OUT_FEAT 64
#define LRELU_ALPHA 0.2f
#define HUB_THRESH 0.01f
#define BITS_STRIDE 320   // ceil(10000/32)=313, padded to 320 words (16B mult)

// workspace layout, in 32-bit words
#define WH_OFF   0          // Wh [10000*64]
#define ESRC_OFF 640000     // e_src [10000]
#define EDST_OFF 650000     // e_dst [10000]
#define T_OFF    660000     // t_j = hub[j]*0.01 [10000]
#define LT_OFF   670000     // log(t_j) [10000]
#define L_OFF    680000     // softmax denom l_i [10000]
#define BITS_OFF 690000     // adjacency bitmask [10000*320] uint32
// total ~15.6 MB

// ---------------------------------------------------------------------------
// Kernel 1: Wh = h @ W  (10000x512x64), e_src = Wh@a_src, e_dst = Wh@a_dst,
// plus (in trailing blocks) t_j and log(t_j) from hub_mask.
// Block: 256 thr = 4 waves. Each block does 16 rows x 64 cols.
// Thread: col = tid&63, rg = tid>>6; owns rows rg, rg+4, rg+8, rg+12.
// ---------------------------------------------------------------------------
__global__ __launch_bounds__(256) void k1_gemm(
    const float* __restrict__ h, const float* __restrict__ W,
    const float* __restrict__ a_src, const float* __restrict__ a_dst,
    const float* __restrict__ hub, float* __restrict__ ws)
{
    const int bx = blockIdx.x, tid = threadIdx.x;
    if (bx >= 625) {
        // hub transform blocks: 10 blocks x 1024 elems
        const int base = (bx - 625) * 1024;
        #pragma unroll
        for (int e = 0; e < 4; ++e) {
            int idx = base + e * 256 + tid;
            if (idx < N_NODES) {
                float t = hub[idx] * HUB_THRESH;
                ws[T_OFF + idx]  = t;
                ws[LT_OFF + idx] = logf(t);   // hub==0 -> -inf: all rows survive, weight p-0
            }
        }
        return;
    }

    __shared__ __align__(16) float Ws[64 * 64];   // [kk][col]
    __shared__ __align__(16) float Hs[16 * 64];   // [r][kk]
    const int col = tid & 63, rg = tid >> 6;
    const int rowBase = bx * 16;                  // 625*16 == 10000 exactly, no tail
    float acc[4] = {0.f, 0.f, 0.f, 0.f};

    for (int k0 = 0; k0 < IN_FEAT; k0 += 64) {
        for (int idx = tid; idx < 4096; idx += 256) {
            int kk = idx >> 6, c = idx & 63;
            Ws[idx] = W[(size_t)(k0 + kk) * 64 + c];          // coalesced
        }
        for (int idx = tid; idx < 1024; idx += 256) {
            int r = idx >> 6, kk = idx & 63;
            Hs[idx] = h[(size_t)(rowBase + r) * IN_FEAT + k0 + kk];  // coalesced
        }
        __syncthreads();
        #pragma unroll
        for (int k4 = 0; k4 < 16; ++k4) {
            // wave-uniform (rg fixed per wave) b128 broadcast reads of Hs
            float4 hv0 = *(const float4*)&Hs[(rg + 0)  * 64 + k4 * 4];
            float4 hv1 = *(const float4*)&Hs[(rg + 4)  * 64 + k4 * 4];
            float4 hv2 = *(const float4*)&Hs[(rg + 8)  * 64 + k4 * 4];
            float4 hv3 = *(const float4*)&Hs[(rg + 12) * 64 + k4 * 4];
            float w0 = Ws[(k4 * 4 + 0) * 64 + col];   // stride-1 across lanes
            float w1 = Ws[(k4 * 4 + 1) * 64 + col];
            float w2 = Ws[(k4 * 4 + 2) * 64 + col];
            float w3 = Ws[(k4 * 4 + 3) * 64 + col];
            acc[0] += hv0.x * w0 + hv0.y * w1 + hv0.z * w2 + hv0.w * w3;
            acc[1] += hv1.x * w0 + hv1.y * w1 + hv1.z * w2 + hv1.w * w3;
            acc[2] += hv2.x * w0 + hv2.y * w1 + hv2.z * w2 + hv2.w * w3;
            acc[3] += hv3.x * w0 + hv3.y * w1 + hv3.z * w2 + hv3.w * w3;
        }
        __syncthreads();
    }

    const float asv = a_src[col], adv = a_dst[col];
    #pragma unroll
    for (int r = 0; r < 4; ++r) {
        int row = rowBase + rg + 4 * r;
        ws[WH_OFF + (size_t)row * 64 + col] = acc[r];        // coalesced
        float s1 = acc[r] * asv, s2 = acc[r] * adv;
        #pragma unroll
        for (int m = 32; m; m >>= 1) {
            s1 += __shfl_xor(s1, m, 64);
            s2 += __shfl_xor(s2, m, 64);
        }
        if (col == 0) {
            ws[ESRC_OFF + row] = s1;
            ws[EDST_OFF + row] = s2;
        }
    }
}

// ---------------------------------------------------------------------------
// Kernel 2: per row i, stream adj[i,:] (the 400 MB), compute
//   l_i = sum_{j: adj>0} exp(lrelu(e_src[i]+e_dst[j]))   (no max needed: |s|<~40)
// and pack adj>0 into a 320-word bitmask row (shfl-OR nibble pack).
// One block (256 thr) per row; 10 iters of int4 = 1024 j per iter.
// ---------------------------------------------------------------------------
__global__ __launch_bounds__(256) void k2_stats(
    const int* __restrict__ adj, float* __restrict__ ws,
    unsigned* __restrict__ wsu)
{
    const int i = blockIdx.x, tid = threadIdx.x;
    const int lane = tid & 63;
    const float esrc = ws[ESRC_OFF + i];
    const float* __restrict__ edst = ws + EDST_OFF;
    const int4* __restrict__ arow = (const int4*)(adj + (size_t)i * N_NODES); // 40000B row: 16B aligned
    unsigned* __restrict__ brow = wsu + BITS_OFF + (size_t)i * BITS_STRIDE;
    float acc = 0.f;

    #pragma unroll
    for (int it = 0; it < 10; ++it) {
        const int j0 = it * 1024 + tid * 4;
        unsigned nib = 0;
        if (j0 < N_NODES) {   // N%4==0 -> full int4 whenever j0<N
            int4 a4  = arow[j0 >> 2];
            float4 e4 = *(const float4*)(edst + j0);
            float s, e;
            s = esrc + e4.x; e = fmaxf(s, LRELU_ALPHA * s);
            if (a4.x > 0) { acc += __expf(e); nib |= 1u; }
            s = esrc + e4.y; e = fmaxf(s, LRELU_ALPHA * s);
            if (a4.y > 0) { acc += __expf(e); nib |= 2u; }
            s = esrc + e4.z; e = fmaxf(s, LRELU_ALPHA * s);
            if (a4.z > 0) { acc += __expf(e); nib |= 4u; }
            s = esrc + e4.w; e = fmaxf(s, LRELU_ALPHA * s);
            if (a4.w > 0) { acc += __expf(e); nib |= 8u; }
        }
        // pack 8 lanes x 4 bits -> one word; bit (j%32) of word (j/32)
        unsigned v = nib << ((lane & 7) * 4);
        v |= (unsigned)__shfl_xor((int)v, 1, 64);
        v |= (unsigned)__shfl_xor((int)v, 2, 64);
        v |= (unsigned)__shfl_xor((int)v, 4, 64);
        if ((lane & 7) == 0) {
            int widx = j0 >> 5;          // multiple-of-32 j0 here
            if (widx < BITS_STRIDE) brow[widx] = v;   // also zero-fills pad words 313..319
        }
    }

    #pragma unroll
    for (int m = 32; m; m >>= 1) acc += __shfl_xor(acc, m, 64);
    __shared__ float part[4];
    if (lane == 0) part[tid >> 6] = acc;
    __syncthreads();
    if (tid == 0) ws[L_OFF + i] = part[0] + part[1] + part[2] + part[3];
}

// ---------------------------------------------------------------------------
// Kernel 3: per row i, scan bitmask; survivor iff adj-bit && p > t_j where
// p = exp(e)/l_i. Log-domain prefilter (e > log l + log t_j - slack) avoids
// exp for ~99% of pairs. Survivors (~100/row) broadcast via ballot+shfl;
// lane owns output column. out = elu(sum w * Wh[j,:]).
// ---------------------------------------------------------------------------
__global__ __launch_bounds__(256) void k3_aggr(
    const float* __restrict__ ws, const unsigned* __restrict__ wsu,
    float* __restrict__ out)
{
    const int i = blockIdx.x, tid = threadIdx.x;
    const int lane = tid & 63, w = tid >> 6;
    const float l = ws[L_OFF + i];
    const float esrc = ws[ESRC_OFF + i];
    const bool empty = (l == 0.0f);               // row w/o neighbors: softmax uniform 1/N
    const float cl = empty ? 0.0f : logf(l);
    const float invN = 1.0f / (float)N_NODES;
    const float* __restrict__ edst  = ws + EDST_OFF;
    const float* __restrict__ tarr  = ws + T_OFF;
    const float* __restrict__ ltarr = ws + LT_OFF;
    const float* __restrict__ Wh    = ws + WH_OFF;
    const unsigned* __restrict__ brow = wsu + BITS_OFF + (size_t)i * BITS_STRIDE;
    float acc = 0.f;

    const int ngroups = (N_NODES + 63) >> 6;      // 157
    for (int g = w; g < ngroups; g += 4) {
        const int j = g * 64 + lane;
        const int jc = j < N_NODES ? j : N_NODES - 1;   // clamp loads in-bounds
        const unsigned word = brow[j >> 5];             // <=313 < 320; pad words are 0
        const bool bit = (word >> (j & 31)) & 1u;
        const float ed = edst[jc];
        const float s = esrc + ed;
        const float e = fmaxf(s, LRELU_ALPHA * s);
        float wgt = 0.0f;
        if (empty) {
            if (j < N_NODES) wgt = fmaxf(invN - tarr[jc], 0.0f);
        } else {
            // prefilter with slack; exact relu(p - t) decides (borderline -> 0 exactly)
            bool cand = (j < N_NODES) && bit && (e > cl + ltarr[jc] - 0.0625f);
            if (cand) {
                float p = __expf(e - cl);               // = exp(e)/l
                wgt = fmaxf(p - tarr[jc], 0.0f);
            }
        }
        unsigned long long mk = __ballot(wgt > 0.0f);
        while (mk) {
            int src = __builtin_ctzll(mk);
            mk &= mk - 1;
            float wv = __shfl(wgt, src, 64);
            int jj = g * 64 + src;
            acc += wv * Wh[(size_t)jj * 64 + lane];     // 256B coalesced, L2-resident
        }
    }

    __shared__ float part[256];
    part[tid] = acc;
    __syncthreads();
    if (w == 0) {
        float tot = part[lane] + part[64 + lane] + part[128 + lane] + part[192 + lane];
        out[(size_t)i * 64 + lane] = tot > 0.0f ? tot : expm1f(tot);   // elu, alpha=1
    }
}

// ---------------------------------------------------------------------------
extern "C" void kernel_launch(void* const* d_in, const int* in_sizes, int n_in,
                              void* d_out, int out_size, void* d_ws, size_t ws_size,
                              hipStream_t stream)
{
    const float* h     = (const float*)d_in[0];
    const float* W     = (const float*)d_in[1];
    const float* a_src = (const float*)d_in[2];
    const float* a_dst = (const float*)d_in[3];
    const float* hub   = (const float*)d_in[4];
    const int*   adj   = (const int*)d_in[5];
    float*    ws  = (float*)d_ws;
    unsigned* wsu = (unsigned*)d_ws;
    float*    out = (float*)d_out;

    k1_gemm<<<635, 256, 0, stream>>>(h, W, a_src, a_dst, hub, ws);
    k2_stats<<<N_NODES, 256, 0, stream>>>(adj, ws, wsu);
    k3_aggr<<<N_NODES, 256, 0, stream>>>(ws, wsu, out);
}

// Round 2
// 673.655 us; speedup vs baseline: 1.0568x; 1.0568x over previous
//
#include <hip/hip_runtime.h>
#include <math.h>

#define N_NODES 10000
#define IN_FEAT 512
#define OUT_FEAT 64
#define LRELU_ALPHA 0.2f
#define HUB_THRESH 0.01f
#define BITS_WORDS 320   // ceil(10000/32)=313, padded to 320 (covered exactly by 10 iters x 32 words)

// workspace layout, in 32-bit words
#define WH_OFF   0          // Wh [10000*64]
#define ESRC_OFF 640000     // e_src [10000]
#define EDST_OFF 650000     // e_dst [10000]
#define T_OFF    660000     // t_j = hub[j]*0.01 [10000]
#define LT_OFF   670000     // log(t_j) [10000]
// total ~2.7 MB

// ---------------------------------------------------------------------------
// Kernel 1: Wh = h @ W  (10000x512x64), e_src = Wh@a_src, e_dst = Wh@a_dst,
// plus (in trailing blocks) t_j and log(t_j) from hub_mask.
// Block: 256 thr = 4 waves. Each block does 16 rows x 64 cols.
// ---------------------------------------------------------------------------
__global__ __launch_bounds__(256) void k1_gemm(
    const float* __restrict__ h, const float* __restrict__ W,
    const float* __restrict__ a_src, const float* __restrict__ a_dst,
    const float* __restrict__ hub, float* __restrict__ ws)
{
    const int bx = blockIdx.x, tid = threadIdx.x;
    if (bx >= 625) {
        const int base = (bx - 625) * 1024;
        #pragma unroll
        for (int e = 0; e < 4; ++e) {
            int idx = base + e * 256 + tid;
            if (idx < N_NODES) {
                float t = hub[idx] * HUB_THRESH;
                ws[T_OFF + idx]  = t;
                ws[LT_OFF + idx] = logf(t);   // hub==0 -> -inf: all neighbors survive prefilter
            }
        }
        return;
    }

    __shared__ __align__(16) float Ws[64 * 64];   // [kk][col]
    __shared__ __align__(16) float Hs[16 * 64];   // [r][kk]
    const int col = tid & 63, rg = tid >> 6;
    const int rowBase = bx * 16;                  // 625*16 == 10000 exactly
    float acc[4] = {0.f, 0.f, 0.f, 0.f};

    for (int k0 = 0; k0 < IN_FEAT; k0 += 64) {
        for (int idx = tid; idx < 4096; idx += 256) {
            int kk = idx >> 6, c = idx & 63;
            Ws[idx] = W[(size_t)(k0 + kk) * 64 + c];
        }
        for (int idx = tid; idx < 1024; idx += 256) {
            int r = idx >> 6, kk = idx & 63;
            Hs[idx] = h[(size_t)(rowBase + r) * IN_FEAT + k0 + kk];
        }
        __syncthreads();
        #pragma unroll
        for (int k4 = 0; k4 < 16; ++k4) {
            float4 hv0 = *(const float4*)&Hs[(rg + 0)  * 64 + k4 * 4];
            float4 hv1 = *(const float4*)&Hs[(rg + 4)  * 64 + k4 * 4];
            float4 hv2 = *(const float4*)&Hs[(rg + 8)  * 64 + k4 * 4];
            float4 hv3 = *(const float4*)&Hs[(rg + 12) * 64 + k4 * 4];
            float w0 = Ws[(k4 * 4 + 0) * 64 + col];
            float w1 = Ws[(k4 * 4 + 1) * 64 + col];
            float w2 = Ws[(k4 * 4 + 2) * 64 + col];
            float w3 = Ws[(k4 * 4 + 3) * 64 + col];
            acc[0] += hv0.x * w0 + hv0.y * w1 + hv0.z * w2 + hv0.w * w3;
            acc[1] += hv1.x * w0 + hv1.y * w1 + hv1.z * w2 + hv1.w * w3;
            acc[2] += hv2.x * w0 + hv2.y * w1 + hv2.z * w2 + hv2.w * w3;
            acc[3] += hv3.x * w0 + hv3.y * w1 + hv3.z * w2 + hv3.w * w3;
        }
        __syncthreads();
    }

    const float asv = a_src[col], adv = a_dst[col];
    #pragma unroll
    for (int r = 0; r < 4; ++r) {
        int row = rowBase + rg + 4 * r;
        ws[WH_OFF + (size_t)row * 64 + col] = acc[r];
        float s1 = acc[r] * asv, s2 = acc[r] * adv;
        #pragma unroll
        for (int m = 32; m; m >>= 1) {
            s1 += __shfl_xor(s1, m, 64);
            s2 += __shfl_xor(s2, m, 64);
        }
        if (col == 0) {
            ws[ESRC_OFF + row] = s1;
            ws[EDST_OFF + row] = s2;
        }
    }
}

// ---------------------------------------------------------------------------
// Kernel 2 (fused): one block (256 thr) per row i.
// Pass A: stream adj[i,:] (the 400 MB, read ONCE), accumulate
//   l_i = sum_{adj>0} exp(lrelu(e_src_i + e_dst_j))   (no max: |s| < ~40)
// and pack adj>0 bits into LDS (313 words = 1.25 KB).
// Pass B: rescan from LDS bits; log-domain prefilter avoids exp for ~99% of
// pairs; survivors (~tens/row) broadcast via ballot+shfl; lane owns the
// output column; out = elu(sum w * Wh[j,:]).
// ---------------------------------------------------------------------------
__global__ __launch_bounds__(256) void k2_fused(
    const int* __restrict__ adj, const float* __restrict__ ws,
    float* __restrict__ out)
{
    const int i = blockIdx.x, tid = threadIdx.x;
    const int lane = tid & 63, w = tid >> 6;
    __shared__ unsigned bits[BITS_WORDS];
    __shared__ float partA[4];
    __shared__ float partB[256];

    const float esrc = ws[ESRC_OFF + i];
    const float* __restrict__ edst = ws + EDST_OFF;
    const int4* __restrict__ arow = (const int4*)(adj + (size_t)i * N_NODES); // 40000 B rows: 16B aligned
    float acc = 0.f;

    // ---- Pass A: stream adj row once ----
    #pragma unroll
    for (int it = 0; it < 10; ++it) {
        const int j0 = it * 1024 + tid * 4;
        unsigned nib = 0;
        if (j0 < N_NODES) {   // N%4==0 -> full int4 whenever j0<N
            int4 a4  = arow[j0 >> 2];
            float4 e4 = *(const float4*)(edst + j0);
            float s, e;
            s = esrc + e4.x; e = fmaxf(s, LRELU_ALPHA * s);
            if (a4.x > 0) { acc += __expf(e); nib |= 1u; }
            s = esrc + e4.y; e = fmaxf(s, LRELU_ALPHA * s);
            if (a4.y > 0) { acc += __expf(e); nib |= 2u; }
            s = esrc + e4.z; e = fmaxf(s, LRELU_ALPHA * s);
            if (a4.z > 0) { acc += __expf(e); nib |= 4u; }
            s = esrc + e4.w; e = fmaxf(s, LRELU_ALPHA * s);
            if (a4.w > 0) { acc += __expf(e); nib |= 8u; }
        }
        // pack 8 lanes x 4 bits -> one word; bit (j%32) of word (j/32).
        // words 0..319 are each written exactly once (it*32 + w*8 + lane/8),
        // pad bits (j>=10000) are 0 via the nib guard.
        unsigned v = nib << ((lane & 7) * 4);
        v |= (unsigned)__shfl_xor((int)v, 1, 64);
        v |= (unsigned)__shfl_xor((int)v, 2, 64);
        v |= (unsigned)__shfl_xor((int)v, 4, 64);
        if ((lane & 7) == 0) bits[j0 >> 5] = v;
    }

    #pragma unroll
    for (int m = 32; m; m >>= 1) acc += __shfl_xor(acc, m, 64);
    if (lane == 0) partA[w] = acc;
    __syncthreads();
    const float l = partA[0] + partA[1] + partA[2] + partA[3];

    // ---- Pass B: aggregate survivors from LDS bits ----
    const bool empty = (l == 0.0f);               // row w/o neighbors: softmax uniform 1/N
    const float cl = empty ? 0.0f : logf(l);
    const float invN = 1.0f / (float)N_NODES;
    const float* __restrict__ tarr  = ws + T_OFF;
    const float* __restrict__ ltarr = ws + LT_OFF;
    const float* __restrict__ Wh    = ws + WH_OFF;
    acc = 0.f;

    const int ngroups = (N_NODES + 63) >> 6;      // 157
    for (int g = w; g < ngroups; g += 4) {
        const int j = g * 64 + lane;
        const int jc = j < N_NODES ? j : N_NODES - 1;   // clamp loads in-bounds
        const unsigned word = bits[j >> 5];             // LDS broadcast; pad words are 0
        const bool bit = (word >> (j & 31)) & 1u;
        const float ed = edst[jc];
        const float s = esrc + ed;
        const float e = fmaxf(s, LRELU_ALPHA * s);
        float wgt = 0.0f;
        if (empty) {
            if (j < N_NODES) wgt = fmaxf(invN - tarr[jc], 0.0f);
        } else {
            // prefilter with slack; exact relu(p - t) decides (borderline -> 0 exactly)
            bool cand = (j < N_NODES) && bit && (e > cl + ltarr[jc] - 0.0625f);
            if (cand) {
                float p = __expf(e - cl);               // = exp(e)/l
                wgt = fmaxf(p - tarr[jc], 0.0f);
            }
        }
        unsigned long long mk = __ballot(wgt > 0.0f);
        while (mk) {
            int src = __builtin_ctzll(mk);
            mk &= mk - 1;
            float wv = __shfl(wgt, src, 64);
            int jj = g * 64 + src;
            acc += wv * Wh[(size_t)jj * 64 + lane];     // 256B coalesced, L2-resident
        }
    }

    partB[tid] = acc;
    __syncthreads();
    if (w == 0) {
        float tot = partB[lane] + partB[64 + lane] + partB[128 + lane] + partB[192 + lane];
        out[(size_t)i * 64 + lane] = tot > 0.0f ? tot : expm1f(tot);   // elu, alpha=1
    }
}

// ---------------------------------------------------------------------------
extern "C" void kernel_launch(void* const* d_in, const int* in_sizes, int n_in,
                              void* d_out, int out_size, void* d_ws, size_t ws_size,
                              hipStream_t stream)
{
    const float* h     = (const float*)d_in[0];
    const float* W     = (const float*)d_in[1];
    const float* a_src = (const float*)d_in[2];
    const float* a_dst = (const float*)d_in[3];
    const float* hub   = (const float*)d_in[4];
    const int*   adj   = (const int*)d_in[5];
    float* ws  = (float*)d_ws;
    float* out = (float*)d_out;

    k1_gemm<<<635, 256, 0, stream>>>(h, W, a_src, a_dst, hub, ws);
    k2_fused<<<N_NODES, 256, 0, stream>>>(adj, ws, out);
}

// Round 3
// 655.131 us; speedup vs baseline: 1.0867x; 1.0283x over previous
//
#include <hip/hip_runtime.h>
#include <math.h>

#define N_NODES 10000
#define IN_FEAT 512
#define OUT_FEAT 64
#define LRELU_ALPHA 0.2f
#define HUB_THRESH 0.01f
#define BITS_WORDS 320   // ceil(10000/32)=313, padded to 320 (10 iters x 32 words)
#define CAND_CAP 1024    // per-chunk candidate list; 256 thr x 4 j => never overflows

// workspace layout, in 32-bit words
#define WH_OFF   0          // Wh [10000*64]
#define ESRC_OFF 640000     // e_src [10000]
#define EDST_OFF 650000     // e_dst [10000]
#define T_OFF    660000     // t_j = hub[j]*0.01 [10000]
#define LT_OFF   670000     // log(t_j) [10000]
// total ~2.7 MB

// ---------------------------------------------------------------------------
// Kernel 1: Wh = h @ W  (10000x512x64), e_src = Wh@a_src, e_dst = Wh@a_dst,
// plus (in trailing blocks) t_j and log(t_j) from hub_mask.
// ---------------------------------------------------------------------------
__global__ __launch_bounds__(256) void k1_gemm(
    const float* __restrict__ h, const float* __restrict__ W,
    const float* __restrict__ a_src, const float* __restrict__ a_dst,
    const float* __restrict__ hub, float* __restrict__ ws)
{
    const int bx = blockIdx.x, tid = threadIdx.x;
    if (bx >= 625) {
        const int base = (bx - 625) * 1024;
        #pragma unroll
        for (int e = 0; e < 4; ++e) {
            int idx = base + e * 256 + tid;
            if (idx < N_NODES) {
                float t = hub[idx] * HUB_THRESH;
                ws[T_OFF + idx]  = t;
                ws[LT_OFF + idx] = logf(t);   // hub==0 -> -inf: prefilter passes, relu decides
            }
        }
        return;
    }

    __shared__ __align__(16) float Ws[64 * 64];   // [kk][col]
    __shared__ __align__(16) float Hs[16 * 64];   // [r][kk]
    const int col = tid & 63, rg = tid >> 6;
    const int rowBase = bx * 16;                  // 625*16 == 10000 exactly
    float acc[4] = {0.f, 0.f, 0.f, 0.f};

    for (int k0 = 0; k0 < IN_FEAT; k0 += 64) {
        for (int idx = tid; idx < 4096; idx += 256) {
            int kk = idx >> 6, c = idx & 63;
            Ws[idx] = W[(size_t)(k0 + kk) * 64 + c];
        }
        for (int idx = tid; idx < 1024; idx += 256) {
            int r = idx >> 6, kk = idx & 63;
            Hs[idx] = h[(size_t)(rowBase + r) * IN_FEAT + k0 + kk];
        }
        __syncthreads();
        #pragma unroll
        for (int k4 = 0; k4 < 16; ++k4) {
            float4 hv0 = *(const float4*)&Hs[(rg + 0)  * 64 + k4 * 4];
            float4 hv1 = *(const float4*)&Hs[(rg + 4)  * 64 + k4 * 4];
            float4 hv2 = *(const float4*)&Hs[(rg + 8)  * 64 + k4 * 4];
            float4 hv3 = *(const float4*)&Hs[(rg + 12) * 64 + k4 * 4];
            float w0 = Ws[(k4 * 4 + 0) * 64 + col];
            float w1 = Ws[(k4 * 4 + 1) * 64 + col];
            float w2 = Ws[(k4 * 4 + 2) * 64 + col];
            float w3 = Ws[(k4 * 4 + 3) * 64 + col];
            acc[0] += hv0.x * w0 + hv0.y * w1 + hv0.z * w2 + hv0.w * w3;
            acc[1] += hv1.x * w0 + hv1.y * w1 + hv1.z * w2 + hv1.w * w3;
            acc[2] += hv2.x * w0 + hv2.y * w1 + hv2.z * w2 + hv2.w * w3;
            acc[3] += hv3.x * w0 + hv3.y * w1 + hv3.z * w2 + hv3.w * w3;
        }
        __syncthreads();
    }

    const float asv = a_src[col], adv = a_dst[col];
    #pragma unroll
    for (int r = 0; r < 4; ++r) {
        int row = rowBase + rg + 4 * r;
        ws[WH_OFF + (size_t)row * 64 + col] = acc[r];
        float s1 = acc[r] * asv, s2 = acc[r] * adv;
        #pragma unroll
        for (int m = 32; m; m >>= 1) {
            s1 += __shfl_xor(s1, m, 64);
            s2 += __shfl_xor(s2, m, 64);
        }
        if (col == 0) {
            ws[ESRC_OFF + row] = s1;
            ws[EDST_OFF + row] = s2;
        }
    }
}

// ---------------------------------------------------------------------------
// Kernel 2 (fused): one block (256 thr) per row i.
// Pass A: stream adj[i,:] once (the 400 MB), accumulate
//   l_i = sum_{adj>0} exp(lrelu(e_src_i + e_dst_j))  (no max: |s| < ~40),
// pack adj>0 bits into LDS.
// Pass B: nibble-chunked rescan (4 j per lane, float4 loads); log-domain
// prefilter kills ~99% of pairs without exp; survivors appended to a
// double-buffered per-chunk LDS candidate list (cap 1024 = structural max),
// then waves split the list: 1 broadcast LDS read + 1 coalesced Wh load + FMA
// per candidate. out = elu(sum w * Wh[j,:]).
// ---------------------------------------------------------------------------
__global__ __launch_bounds__(256) void k2_fused(
    const int* __restrict__ adj, const float* __restrict__ ws,
    float* __restrict__ out)
{
    const int i = blockIdx.x, tid = threadIdx.x;
    const int lane = tid & 63, w = tid >> 6;
    __shared__ unsigned bits[BITS_WORDS];
    __shared__ float partA[4];
    __shared__ float partB[256];
    __shared__ int   candj[2][CAND_CAP];
    __shared__ float candw[2][CAND_CAP];
    __shared__ int   cnt[10];

    const float esrc = ws[ESRC_OFF + i];
    const float* __restrict__ edst = ws + EDST_OFF;
    const int4* __restrict__ arow = (const int4*)(adj + (size_t)i * N_NODES); // 40000 B rows: 16B aligned
    float acc = 0.f;

    if (tid < 10) cnt[tid] = 0;

    // ---- Pass A: stream adj row once ----
    #pragma unroll
    for (int it = 0; it < 10; ++it) {
        const int j0 = it * 1024 + tid * 4;
        unsigned nib = 0;
        if (j0 < N_NODES) {   // N%4==0 -> full int4 whenever j0<N
            int4 a4  = arow[j0 >> 2];
            float4 e4 = *(const float4*)(edst + j0);
            float s, e;
            s = esrc + e4.x; e = fmaxf(s, LRELU_ALPHA * s);
            if (a4.x > 0) { acc += __expf(e); nib |= 1u; }
            s = esrc + e4.y; e = fmaxf(s, LRELU_ALPHA * s);
            if (a4.y > 0) { acc += __expf(e); nib |= 2u; }
            s = esrc + e4.z; e = fmaxf(s, LRELU_ALPHA * s);
            if (a4.z > 0) { acc += __expf(e); nib |= 4u; }
            s = esrc + e4.w; e = fmaxf(s, LRELU_ALPHA * s);
            if (a4.w > 0) { acc += __expf(e); nib |= 8u; }
        }
        // pack 8 lanes x 4 bits -> one word; each word 0..319 written once;
        // pad bits (j>=10000) are 0 via the nib guard.
        unsigned v = nib << ((lane & 7) * 4);
        v |= (unsigned)__shfl_xor((int)v, 1, 64);
        v |= (unsigned)__shfl_xor((int)v, 2, 64);
        v |= (unsigned)__shfl_xor((int)v, 4, 64);
        if ((lane & 7) == 0) bits[j0 >> 5] = v;
    }

    #pragma unroll
    for (int m = 32; m; m >>= 1) acc += __shfl_xor(acc, m, 64);
    if (lane == 0) partA[w] = acc;
    __syncthreads();
    const float l = partA[0] + partA[1] + partA[2] + partA[3];

    // ---- Pass B ----
    const bool empty = (l == 0.0f);               // row w/o neighbors: softmax uniform 1/N
    const float cl = empty ? 0.0f : logf(l);
    const float invN = 1.0f / (float)N_NODES;
    const float thr = cl - 0.0625f;               // prefilter slack
    const float* __restrict__ tarr  = ws + T_OFF;
    const float* __restrict__ ltarr = ws + LT_OFF;
    const float* __restrict__ Wh    = ws + WH_OFF;
    float oacc = 0.f;

    for (int it = 0; it < 10; ++it) {
        const int buf = it & 1;
        const int j0 = it * 1024 + tid * 4;
        if (j0 < N_NODES) {
            if (!empty) {
                const unsigned word = bits[j0 >> 5];
                const unsigned nib = (word >> (j0 & 31)) & 0xFu;   // j0%32 is mult of 4
                if (nib) {
                    float4 e4  = *(const float4*)(edst + j0);
                    float4 lt4 = *(const float4*)(ltarr + j0);
                    #pragma unroll
                    for (int c = 0; c < 4; ++c) {
                        if (nib & (1u << c)) {
                            float ed = (c == 0) ? e4.x : (c == 1) ? e4.y : (c == 2) ? e4.z : e4.w;
                            float lt = (c == 0) ? lt4.x : (c == 1) ? lt4.y : (c == 2) ? lt4.z : lt4.w;
                            float s = esrc + ed;
                            float e = fmaxf(s, LRELU_ALPHA * s);
                            if (e > thr + lt) {                     // rare
                                float p = __expf(e - cl);           // = exp(e)/l
                                float wgt = p - tarr[j0 + c];       // exact relu decides
                                if (wgt > 0.0f) {
                                    int k = atomicAdd(&cnt[it], 1); // k < 1024 structurally
                                    candj[buf][k] = j0 + c;
                                    candw[buf][k] = wgt;
                                }
                            }
                        }
                    }
                }
            } else {
                float4 t4 = *(const float4*)(tarr + j0);
                #pragma unroll
                for (int c = 0; c < 4; ++c) {
                    float tv = (c == 0) ? t4.x : (c == 1) ? t4.y : (c == 2) ? t4.z : t4.w;
                    float wgt = invN - tv;
                    if (wgt > 0.0f) {
                        int k = atomicAdd(&cnt[it], 1);
                        candj[buf][k] = j0 + c;
                        candw[buf][k] = wgt;
                    }
                }
            }
        }
        __syncthreads();   // list for chunk `it` complete; next chunk uses other buffer
        const int M = cnt[it];
        for (int c = w; c < M; c += 4) {
            int   jj = candj[buf][c];   // wave-uniform LDS broadcast
            float wv = candw[buf][c];
            oacc += wv * Wh[(size_t)jj * 64 + lane];   // 256B coalesced, L2-resident
        }
        // no barrier needed: a wave that races ahead scans chunk it+1 into the
        // OTHER buffer (own atomic slot), then waits at that chunk's barrier.
    }

    partB[tid] = oacc;
    __syncthreads();
    if (w == 0) {
        float tot = partB[lane] + partB[64 + lane] + partB[128 + lane] + partB[192 + lane];
        out[(size_t)i * 64 + lane] = tot > 0.0f ? tot : expm1f(tot);   // elu, alpha=1
    }
}

// ---------------------------------------------------------------------------
extern "C" void kernel_launch(void* const* d_in, const int* in_sizes, int n_in,
                              void* d_out, int out_size, void* d_ws, size_t ws_size,
                              hipStream_t stream)
{
    const float* h     = (const float*)d_in[0];
    const float* W     = (const float*)d_in[1];
    const float* a_src = (const float*)d_in[2];
    const float* a_dst = (const float*)d_in[3];
    const float* hub   = (const float*)d_in[4];
    const int*   adj   = (const int*)d_in[5];
    float* ws  = (float*)d_ws;
    float* out = (float*)d_out;

    k1_gemm<<<635, 256, 0, stream>>>(h, W, a_src, a_dst, hub, ws);
    k2_fused<<<N_NODES, 256, 0, stream>>>(adj, ws, out);
}

// Round 4
// 629.850 us; speedup vs baseline: 1.1303x; 1.0401x over previous
//
#include <hip/hip_runtime.h>
#include <math.h>

#define N_NODES 10000
#define IN_FEAT 512
#define OUT_FEAT 64
#define LRELU_ALPHA 0.2f
#define HUB_THRESH 0.01f
#define BITS_WORDS 320   // ceil(10000/32)=313, padded to 320 (10 iters x 32 words)
#define CAND_CAP 1024    // per-row per-chunk list; 256 thr x 4 j => never overflows

// workspace layout, in 32-bit words
#define WH_OFF   0          // Wh [10000*64]
#define ESRC_OFF 640000     // e_src [10000]
#define EDST_OFF 650000     // e_dst [10000]
#define T_OFF    660000     // t_j = hub[j]*0.01 [10000]
#define LT_OFF   670000     // log(t_j) [10000]
// total ~2.7 MB

// ---------------------------------------------------------------------------
// Kernel 1: Wh = h @ W  (10000x512x64), e_src = Wh@a_src, e_dst = Wh@a_dst,
// plus (in trailing blocks) t_j and log(t_j) from hub_mask.
// ---------------------------------------------------------------------------
__global__ __launch_bounds__(256) void k1_gemm(
    const float* __restrict__ h, const float* __restrict__ W,
    const float* __restrict__ a_src, const float* __restrict__ a_dst,
    const float* __restrict__ hub, float* __restrict__ ws)
{
    const int bx = blockIdx.x, tid = threadIdx.x;
    if (bx >= 625) {
        const int base = (bx - 625) * 1024;
        #pragma unroll
        for (int e = 0; e < 4; ++e) {
            int idx = base + e * 256 + tid;
            if (idx < N_NODES) {
                float t = hub[idx] * HUB_THRESH;
                ws[T_OFF + idx]  = t;
                ws[LT_OFF + idx] = logf(t);   // hub==0 -> -inf: prefilter passes, relu decides
            }
        }
        return;
    }

    __shared__ __align__(16) float Ws[64 * 64];   // [kk][col]
    __shared__ __align__(16) float Hs[16 * 64];   // [r][kk]
    const int col = tid & 63, rg = tid >> 6;
    const int rowBase = bx * 16;                  // 625*16 == 10000 exactly
    float acc[4] = {0.f, 0.f, 0.f, 0.f};

    for (int k0 = 0; k0 < IN_FEAT; k0 += 64) {
        for (int idx = tid; idx < 4096; idx += 256) {
            int kk = idx >> 6, c = idx & 63;
            Ws[idx] = W[(size_t)(k0 + kk) * 64 + c];
        }
        for (int idx = tid; idx < 1024; idx += 256) {
            int r = idx >> 6, kk = idx & 63;
            Hs[idx] = h[(size_t)(rowBase + r) * IN_FEAT + k0 + kk];
        }
        __syncthreads();
        #pragma unroll
        for (int k4 = 0; k4 < 16; ++k4) {
            float4 hv0 = *(const float4*)&Hs[(rg + 0)  * 64 + k4 * 4];
            float4 hv1 = *(const float4*)&Hs[(rg + 4)  * 64 + k4 * 4];
            float4 hv2 = *(const float4*)&Hs[(rg + 8)  * 64 + k4 * 4];
            float4 hv3 = *(const float4*)&Hs[(rg + 12) * 64 + k4 * 4];
            float w0 = Ws[(k4 * 4 + 0) * 64 + col];
            float w1 = Ws[(k4 * 4 + 1) * 64 + col];
            float w2 = Ws[(k4 * 4 + 2) * 64 + col];
            float w3 = Ws[(k4 * 4 + 3) * 64 + col];
            acc[0] += hv0.x * w0 + hv0.y * w1 + hv0.z * w2 + hv0.w * w3;
            acc[1] += hv1.x * w0 + hv1.y * w1 + hv1.z * w2 + hv1.w * w3;
            acc[2] += hv2.x * w0 + hv2.y * w1 + hv2.z * w2 + hv2.w * w3;
            acc[3] += hv3.x * w0 + hv3.y * w1 + hv3.z * w2 + hv3.w * w3;
        }
        __syncthreads();
    }

    const float asv = a_src[col], adv = a_dst[col];
    #pragma unroll
    for (int r = 0; r < 4; ++r) {
        int row = rowBase + rg + 4 * r;
        ws[WH_OFF + (size_t)row * 64 + col] = acc[r];
        float s1 = acc[r] * asv, s2 = acc[r] * adv;
        #pragma unroll
        for (int m = 32; m; m >>= 1) {
            s1 += __shfl_xor(s1, m, 64);
            s2 += __shfl_xor(s2, m, 64);
        }
        if (col == 0) {
            ws[ESRC_OFF + row] = s1;
            ws[EDST_OFF + row] = s2;
        }
    }
}

// ---------------------------------------------------------------------------
// Kernel 2 (fused, 2 rows/block): block b handles rows i0=2b, i1=2b+1.
// Pass A: stream both adj rows once (the 400 MB total), shared edst loads;
//   l_r = sum_{adj>0} exp(lrelu(esrc_r + edst_j)); bits packed into LDS.
// Pass B: shared nibble scan (edst/lt float4 loads amortized over 2 rows);
// log-domain prefilter; survivors into per-row int2 LDS lists (cap 1024 =
// structural max); waves split lists: broadcast LDS read + coalesced Wh load.
// Epilogue buffer aliases `bits` to keep LDS <= ~19 KB (8 blocks/CU).
// ---------------------------------------------------------------------------
__global__ __launch_bounds__(256) void k2_fused(
    const int* __restrict__ adj, const float* __restrict__ ws,
    float* __restrict__ out)
{
    const int b = blockIdx.x, tid = threadIdx.x;
    const int lane = tid & 63, w = tid >> 6;
    const int i0 = 2 * b, i1 = 2 * b + 1;
    __shared__ unsigned bits[2][BITS_WORDS];   // 2560 B; aliased as partB in epilogue
    __shared__ float partA[2][4];
    __shared__ int2  cand[2][CAND_CAP];        // 16 KB
    __shared__ int   cnt[2][10];

    const float esrc0 = ws[ESRC_OFF + i0];
    const float esrc1 = ws[ESRC_OFF + i1];
    const float* __restrict__ edst = ws + EDST_OFF;
    const int4* __restrict__ arow0 = (const int4*)(adj + (size_t)i0 * N_NODES); // 40000 B rows: 16B aligned
    const int4* __restrict__ arow1 = (const int4*)(adj + (size_t)i1 * N_NODES);
    float acc0 = 0.f, acc1 = 0.f;

    if (tid < 20) ((int*)cnt)[tid] = 0;        // visible after pass-A barrier

    // ---- Pass A: stream both adj rows once ----
    #pragma unroll 2
    for (int it = 0; it < 10; ++it) {
        const int j0 = it * 1024 + tid * 4;
        unsigned nib0 = 0, nib1 = 0;
        if (j0 < N_NODES) {   // N%4==0 -> full int4 whenever j0<N
            int4 a0 = arow0[j0 >> 2];
            int4 a1 = arow1[j0 >> 2];
            float4 e4 = *(const float4*)(edst + j0);
            float s, e;
            s = esrc0 + e4.x; e = fmaxf(s, LRELU_ALPHA * s);
            if (a0.x > 0) { acc0 += __expf(e); nib0 |= 1u; }
            s = esrc0 + e4.y; e = fmaxf(s, LRELU_ALPHA * s);
            if (a0.y > 0) { acc0 += __expf(e); nib0 |= 2u; }
            s = esrc0 + e4.z; e = fmaxf(s, LRELU_ALPHA * s);
            if (a0.z > 0) { acc0 += __expf(e); nib0 |= 4u; }
            s = esrc0 + e4.w; e = fmaxf(s, LRELU_ALPHA * s);
            if (a0.w > 0) { acc0 += __expf(e); nib0 |= 8u; }
            s = esrc1 + e4.x; e = fmaxf(s, LRELU_ALPHA * s);
            if (a1.x > 0) { acc1 += __expf(e); nib1 |= 1u; }
            s = esrc1 + e4.y; e = fmaxf(s, LRELU_ALPHA * s);
            if (a1.y > 0) { acc1 += __expf(e); nib1 |= 2u; }
            s = esrc1 + e4.z; e = fmaxf(s, LRELU_ALPHA * s);
            if (a1.z > 0) { acc1 += __expf(e); nib1 |= 4u; }
            s = esrc1 + e4.w; e = fmaxf(s, LRELU_ALPHA * s);
            if (a1.w > 0) { acc1 += __expf(e); nib1 |= 8u; }
        }
        // pack 8 lanes x 4 bits -> one word per row; each word written once;
        // pad bits (j>=10000) are 0 via the nib guard.
        unsigned v0 = nib0 << ((lane & 7) * 4);
        unsigned v1 = nib1 << ((lane & 7) * 4);
        v0 |= (unsigned)__shfl_xor((int)v0, 1, 64);
        v1 |= (unsigned)__shfl_xor((int)v1, 1, 64);
        v0 |= (unsigned)__shfl_xor((int)v0, 2, 64);
        v1 |= (unsigned)__shfl_xor((int)v1, 2, 64);
        v0 |= (unsigned)__shfl_xor((int)v0, 4, 64);
        v1 |= (unsigned)__shfl_xor((int)v1, 4, 64);
        if ((lane & 7) == 0) {
            bits[0][j0 >> 5] = v0;
            bits[1][j0 >> 5] = v1;
        }
    }

    #pragma unroll
    for (int m = 32; m; m >>= 1) {
        acc0 += __shfl_xor(acc0, m, 64);
        acc1 += __shfl_xor(acc1, m, 64);
    }
    if (lane == 0) { partA[0][w] = acc0; partA[1][w] = acc1; }
    __syncthreads();
    const float l0 = partA[0][0] + partA[0][1] + partA[0][2] + partA[0][3];
    const float l1 = partA[1][0] + partA[1][1] + partA[1][2] + partA[1][3];

    // ---- Pass B ----
    const bool empty0 = (l0 == 0.0f), empty1 = (l1 == 0.0f);  // rows w/o neighbors: uniform 1/N
    const float cl0 = empty0 ? 0.0f : logf(l0);
    const float cl1 = empty1 ? 0.0f : logf(l1);
    const float thr0 = cl0 - 0.0625f, thr1 = cl1 - 0.0625f;   // prefilter slack
    const float invN = 1.0f / (float)N_NODES;
    const float* __restrict__ tarr  = ws + T_OFF;
    const float* __restrict__ ltarr = ws + LT_OFF;
    const float* __restrict__ Wh    = ws + WH_OFF;
    float oacc0 = 0.f, oacc1 = 0.f;

    for (int it = 0; it < 10; ++it) {
        const int j0 = it * 1024 + tid * 4;
        unsigned m0 = 0, m1 = 0;
        if (j0 < N_NODES) {
            m0 = empty0 ? 0u : (bits[0][j0 >> 5] >> (j0 & 31)) & 0xFu;  // j0%32 mult of 4
            m1 = empty1 ? 0u : (bits[1][j0 >> 5] >> (j0 & 31)) & 0xFu;
        }
        if (m0 | m1) {
            float4 e4  = *(const float4*)(edst + j0);
            float4 lt4 = *(const float4*)(ltarr + j0);
            #pragma unroll
            for (int c = 0; c < 4; ++c) {
                float ed = (c == 0) ? e4.x  : (c == 1) ? e4.y  : (c == 2) ? e4.z  : e4.w;
                float lt = (c == 0) ? lt4.x : (c == 1) ? lt4.y : (c == 2) ? lt4.z : lt4.w;
                if (m0 & (1u << c)) {
                    float s = esrc0 + ed;
                    float e = fmaxf(s, LRELU_ALPHA * s);
                    if (e > thr0 + lt) {                      // rare
                        float p = __expf(e - cl0);            // = exp(e)/l0
                        float wgt = p - tarr[j0 + c];         // exact relu decides
                        if (wgt > 0.0f) {
                            int k = atomicAdd(&cnt[0][it], 1);
                            cand[0][k] = make_int2(j0 + c, __float_as_int(wgt));
                        }
                    }
                }
                if (m1 & (1u << c)) {
                    float s = esrc1 + ed;
                    float e = fmaxf(s, LRELU_ALPHA * s);
                    if (e > thr1 + lt) {
                        float p = __expf(e - cl1);
                        float wgt = p - tarr[j0 + c];
                        if (wgt > 0.0f) {
                            int k = atomicAdd(&cnt[1][it], 1);
                            cand[1][k] = make_int2(j0 + c, __float_as_int(wgt));
                        }
                    }
                }
            }
        }
        if ((empty0 | empty1) && j0 < N_NODES) {   // block-uniform; dead for this data
            float4 t4 = *(const float4*)(tarr + j0);
            #pragma unroll
            for (int c = 0; c < 4; ++c) {
                float tv = (c == 0) ? t4.x : (c == 1) ? t4.y : (c == 2) ? t4.z : t4.w;
                float wv = invN - tv;
                if (wv > 0.0f) {
                    if (empty0) {
                        int k = atomicAdd(&cnt[0][it], 1);
                        cand[0][k] = make_int2(j0 + c, __float_as_int(wv));
                    }
                    if (empty1) {
                        int k = atomicAdd(&cnt[1][it], 1);
                        cand[1][k] = make_int2(j0 + c, __float_as_int(wv));
                    }
                }
            }
        }
        __syncthreads();   // lists for chunk `it` complete
        const int M0 = cnt[0][it], M1 = cnt[1][it];
        for (int c = w; c < M0; c += 4) {
            int2 cd = cand[0][c];                            // wave-uniform LDS broadcast
            oacc0 += __int_as_float(cd.y) * Wh[(size_t)cd.x * 64 + lane];  // 256B coalesced, L2-hit
        }
        for (int c = w; c < M1; c += 4) {
            int2 cd = cand[1][c];
            oacc1 += __int_as_float(cd.y) * Wh[(size_t)cd.x * 64 + lane];
        }
        __syncthreads();   // lists consumed before next chunk overwrites
    }

    // epilogue: alias bits (2560 B >= 512 floats); barrier above fences reuse
    float* partB = (float*)bits;
    partB[tid]       = oacc0;
    partB[256 + tid] = oacc1;
    __syncthreads();
    if (w < 2) {
        const float* pb = partB + w * 256;
        float tot = pb[lane] + pb[64 + lane] + pb[128 + lane] + pb[192 + lane];
        out[(size_t)(i0 + w) * 64 + lane] = tot > 0.0f ? tot : expm1f(tot);   // elu, alpha=1
    }
}

// ---------------------------------------------------------------------------
extern "C" void kernel_launch(void* const* d_in, const int* in_sizes, int n_in,
                              void* d_out, int out_size, void* d_ws, size_t ws_size,
                              hipStream_t stream)
{
    const float* h     = (const float*)d_in[0];
    const float* W     = (const float*)d_in[1];
    const float* a_src = (const float*)d_in[2];
    const float* a_dst = (const float*)d_in[3];
    const float* hub   = (const float*)d_in[4];
    const int*   adj   = (const int*)d_in[5];
    float* ws  = (float*)d_ws;
    float* out = (float*)d_out;

    k1_gemm<<<635, 256, 0, stream>>>(h, W, a_src, a_dst, hub, ws);
    k2_fused<<<N_NODES / 2, 256, 0, stream>>>(adj, ws, out);
}